// Round 1
// baseline (27.714 us; speedup 1.0000x reference)
//
#include <hip/hip_runtime.h>

// EquivariantMultiheadAttention — B=4, N=128, S=8, CIN=COUT=8, GDIM=7
//
// Math: softmax over key dims (j,s2) lets the query factor exp(y_i*w_y1) and
// the biases exp(b_g+b_y) cancel exactly. So:
//   out[b,i,s1,c] = ( y[b,i,s1,c] + num/den ) * mask[b,i,s1]
//   num = sum_{j,s2} exp(g.wg[c]) * keyw * y[b,j,s2,c]
//   den = sum_{j,s2} exp(g.wg[c]) * keyw
//   keyw = mask[b,j,s2] ? exp(y[b,j,s2,c]*w_y[c,0]) : 0
// then out @ w_lin^T.
//
// One workgroup per (b,i): reads the contiguous 224 KB slab of pairwise_g.

namespace {

constexpr int kB = 4, kN = 128, kS = 8, kC = 8, kO = 8, kG = 7;
// LDS row stride per j: 64 payload + 4 pad. 68*4 = 272 B = 17*16 -> float4
// aligned, and 68 % 32 = 4 -> the 8 concurrently-read j-rows land on banks
// {0,4,...,28}: a ds_read_b128 per row covers 4 banks, 8 rows cover all 32.
constexpr int JSTRIDE = 68;

__global__ __launch_bounds__(256, 2)
void emha_kernel(const float* __restrict__ pg,     // (B,N,N,S,S,G)
                 const float* __restrict__ y,      // (B,N,S,C)
                 const int*   __restrict__ mask,   // (B,N,S) 0/1
                 const float* __restrict__ w_y,    // (C,2)
                 const float* __restrict__ w_g,    // (C,G)
                 const float* __restrict__ w_lin,  // (O,C)
                 float*       __restrict__ out)    // (B,N,S,O)
{
    __shared__ float lds_kw[kN * JSTRIDE];   // keyw[j][s2*8+c]
    __shared__ float lds_kv[kN * JSTRIDE];   // keyw*y
    __shared__ float red[4][8][16];          // wave, s1, {num[8],den[8]}
    __shared__ float obuf[8][8];             // s1, c

    const int t  = threadIdx.x;
    const int bi = blockIdx.x;               // b*N + i
    const int b  = bi >> 7;
    const int i  = bi & 127;

    // uniform weights (uniform addresses -> scalar loads)
    float wg[kC][kG];
#pragma unroll
    for (int c = 0; c < kC; ++c)
#pragma unroll
        for (int g = 0; g < kG; ++g)
            wg[c][g] = w_g[c * kG + g];

    // ---- Phase 1: key tables for batch b (8192 items, 32/thread) ----
    const float* yb = y    + b * (kN * kS * kC);
    const int*   mb = mask + b * (kN * kS);
    const float  wy0 = w_y[2 * (t & 7)];     // c = idx&7 == t&7 for all k
#pragma unroll
    for (int k = 0; k < 32; ++k) {
        const int idx = t + k * 256;         // j*64 + s2*8 + c
        const float yv = yb[idx];            // coalesced
        const int   m  = mb[idx >> 3];
        const float kw = m ? __expf(yv * wy0) : 0.0f;
        const int off = (idx >> 6) * JSTRIDE + (idx & 63);
        lds_kw[off] = kw;
        lds_kv[off] = kw * yv;
    }
    __syncthreads();

    // ---- Phase 2: main sweep over the (j,s1,s2) slab ----
    const float* pbase = pg + (size_t)bi * (kN * kS * kS * kG);
    const int s1 = t & 7;                    // fixed query sample per thread
    float num[kC], den[kC];
#pragma unroll
    for (int c = 0; c < kC; ++c) { num[c] = 0.0f; den[c] = 0.0f; }

#pragma unroll
    for (int k = 0; k < 4; ++k) {
        const int j    = k * 32 + (t >> 3);
        const int pair = k * 256 + t;        // j*8 + s1
        const float4* src = reinterpret_cast<const float4*>(pbase + (size_t)pair * 56);
        float p[56];                         // all g-data for (j,s1): 14 x float4
#pragma unroll
        for (int q = 0; q < 14; ++q)
            reinterpret_cast<float4*>(p)[q] = src[q];

#pragma unroll
        for (int s2 = 0; s2 < kS; ++s2) {
            const int lo = j * JSTRIDE + s2 * 8;
            const float4 kva = *reinterpret_cast<const float4*>(&lds_kv[lo]);
            const float4 kvb = *reinterpret_cast<const float4*>(&lds_kv[lo + 4]);
            const float4 kwa = *reinterpret_cast<const float4*>(&lds_kw[lo]);
            const float4 kwb = *reinterpret_cast<const float4*>(&lds_kw[lo + 4]);
            const float kv[8] = {kva.x, kva.y, kva.z, kva.w, kvb.x, kvb.y, kvb.z, kvb.w};
            const float kw[8] = {kwa.x, kwa.y, kwa.z, kwa.w, kwb.x, kwb.y, kwb.z, kwb.w};
#pragma unroll
            for (int c = 0; c < kC; ++c) {
                float d =      p[s2 * kG + 0] * wg[c][0];
                d = fmaf(p[s2 * kG + 1], wg[c][1], d);
                d = fmaf(p[s2 * kG + 2], wg[c][2], d);
                d = fmaf(p[s2 * kG + 3], wg[c][3], d);
                d = fmaf(p[s2 * kG + 4], wg[c][4], d);
                d = fmaf(p[s2 * kG + 5], wg[c][5], d);
                d = fmaf(p[s2 * kG + 6], wg[c][6], d);
                const float e = __expf(d);
                num[c] = fmaf(e, kv[c], num[c]);
                den[c] = fmaf(e, kw[c], den[c]);
            }
        }
    }

    // ---- Phase 3: reduce 32 threads per s1 ----
    // in-wave: lanes {s1, s1+8, ..., s1+56} share s1 -> butterfly over 8,16,32
#pragma unroll
    for (int c = 0; c < kC; ++c) {
        num[c] += __shfl_xor(num[c], 8);
        num[c] += __shfl_xor(num[c], 16);
        num[c] += __shfl_xor(num[c], 32);
        den[c] += __shfl_xor(den[c], 8);
        den[c] += __shfl_xor(den[c], 16);
        den[c] += __shfl_xor(den[c], 32);
    }
    const int wave = t >> 6;
    const int lane = t & 63;
    if (lane < 8) {
#pragma unroll
        for (int c = 0; c < kC; ++c) {
            red[wave][lane][c]     = num[c];
            red[wave][lane][c + 8] = den[c];
        }
    }
    __syncthreads();

    // ---- Phase 4: cross-wave reduce + residual + query mask ----
    if (t < 64) {
        const int s1q = t >> 3, c = t & 7;
        float ns = 0.0f, ds = 0.0f;
#pragma unroll
        for (int w = 0; w < 4; ++w) { ns += red[w][s1q][c]; ds += red[w][s1q][c + 8]; }
        const float yv = yb[(i * kS + s1q) * kC + c];
        const int   m  = mb[i * kS + s1q];
        obuf[s1q][c] = m ? (yv + ns / ds) : 0.0f;
    }
    __syncthreads();

    // ---- Phase 5: output linear (c -> o), coalesced 64-float store ----
    if (t < 64) {
        const int s1q = t >> 3, o = t & 7;
        float acc = 0.0f;
#pragma unroll
        for (int c = 0; c < kC; ++c)
            acc = fmaf(obuf[s1q][c], w_lin[o * kC + c], acc);
        out[(size_t)bi * (kS * kO) + t] = acc;
    }
}

} // namespace

extern "C" void kernel_launch(void* const* d_in, const int* in_sizes, int n_in,
                              void* d_out, int out_size, void* d_ws, size_t ws_size,
                              hipStream_t stream)
{
    const float* pg    = (const float*)d_in[0];  // pairwise_g
    const float* y     = (const float*)d_in[1];  // coset_functions
    const int*   mask  = (const int*)  d_in[2];  // mask (bool -> int32)
    const float* w_y   = (const float*)d_in[3];
    // d_in[4] = b_y, d_in[6] = b_g: cancel in the softmax -> unused
    const float* w_g   = (const float*)d_in[5];
    const float* w_lin = (const float*)d_in[7];
    float* out = (float*)d_out;

    emha_kernel<<<kB * kN, 256, 0, stream>>>(pg, y, mask, w_y, w_g, w_lin, out);
}